// Round 6
// baseline (71079.584 us; speedup 1.0000x reference)
//
#include <hip/hip_runtime.h>

#define T_STEPS 16384
#define N 2048
#define NBLK 64           // consumers of the g-image: 64 x 16 KB = 1 MB/step
#define THREADS 512       // 8 waves; wave owns 4 columns
#define COLS 32           // columns per block
#define NSLOT 4           // g ring slots; blocks stay within 1 step

typedef unsigned long long u64;

// ---------------------------------------------------------------------------
// Protocol (proven rounds 3/4): publish p = g entering step p, stored in
// slots[p&3][j] as one aligned 8B pair (low 32: g bits, high 32: tag p+1).
// The 8B store is naturally atomic => tag fresh <=> g fresh, one coherent hop,
// no fences. Poll at step t waits for tag t+1 on all 2048 pairs. Ring safety:
// publish t+1 overwrites publish t-3, whose readers (step t-3 polls) are all
// done because poll(t) succeeded. Tags monotonic 1..T+1; zeroed slots (memset)
// match nothing. Agent-scope relaxed atomics bypass non-coherent per-XCD L2s.
// ---------------------------------------------------------------------------

__global__ void __launch_bounds__(THREADS, 2)
lif_kernel(const float* __restrict__ x_in, const float* __restrict__ w,
           const float* __restrict__ E_L, const float* __restrict__ tau_m,
           const float* __restrict__ R_I, const float* __restrict__ tau_g,
           const float* __restrict__ v0,  const float* __restrict__ g0,
           float* __restrict__ out, u64* __restrict__ slots)
{
    __shared__ float g_lds[2][N];   // 16 KB double-buffered g image (only LDS)

    const int tid = threadIdx.x;
    const int blk = blockIdx.x;
    const int j0  = blk * COLS;
    const int wv  = tid >> 6;       // wave 0..7
    const int ln  = tid & 63;
    const int jc0 = j0 + wv * 4;    // wave's first column

    // ---- one-time: w into registers, DIRECT from global (no LDS staging).
    //      wrow[k] = w[ln + k*64][jc0 .. jc0+3] (contiguous cols = one float4),
    //      diagonal zeroed per component. 128 VGPRs. ----
    float4 wrow[32];
    #pragma unroll
    for (int k = 0; k < 32; ++k) {
        int r = ln + k * 64;
        float4 v4 = *reinterpret_cast<const float4*>(w + (size_t)r * N + jc0);
        int d = r - jc0;            // diagonal hits component d if 0<=d<4
        if (d == 0) v4.x = 0.0f;
        else if (d == 1) v4.y = 0.0f;
        else if (d == 2) v4.z = 0.0f;
        else if (d == 3) v4.w = 0.0f;
        wrow[k] = v4;
    }

    // owner lane 0 of each wave keeps its 4 neurons' state (unrolled indices)
    const bool own = (ln == 0);
    float v_st[4], g_st[4], eL[4], tm[4], ri[4], tg[4], xv[4];
    if (own) {
        #pragma unroll
        for (int c = 0; c < 4; ++c) {
            int j = jc0 + c;
            v_st[c] = v0[j]; g_st[c] = g0[j];
            eL[c] = E_L[j]; tm[c] = tau_m[j]; ri[c] = R_I[j]; tg[c] = tau_g[j];
            xv[c] = x_in[j];                       // t=0 input
            __hip_atomic_store(&slots[j],          // publish 0: slot 0, tag 1
                ((u64)1u << 32) | (u64)__float_as_uint(g_st[c]),
                __ATOMIC_RELAXED, __HIP_MEMORY_SCOPE_AGENT);
        }
    }

    for (int t = 0; t < T_STEPS; ++t) {
        const u64* slot = slots + (size_t)(t & 3) * N;
        const unsigned tgt = (unsigned)(t + 1);

        // ---- poll own 4 pairs; retries touch only stale pairs ----
        float gp[4];
        unsigned pend = 0xFu;
        for (;;) {
            #pragma unroll
            for (int u = 0; u < 4; ++u) {
                if (pend & (1u << u)) {
                    u64 p = __hip_atomic_load(&slot[tid + u * 512],
                                              __ATOMIC_RELAXED,
                                              __HIP_MEMORY_SCOPE_AGENT);
                    if ((unsigned)(p >> 32) == tgt) {
                        gp[u] = __uint_as_float((unsigned)p);
                        pend &= ~(1u << u);
                    }
                }
            }
            if (!__any(pend != 0)) break;
            __builtin_amdgcn_s_sleep(1);
        }

        // ---- share to LDS (stride-1 across lanes, conflict-free) ----
        float* gl = g_lds[t & 1];
        #pragma unroll
        for (int u = 0; u < 4; ++u)
            gl[tid + u * 512] = gp[u];
        __syncthreads();

        // ---- matvec: 4 cols/wave as float4, 32 rows/lane, w in regs ----
        float4 acc = {0.f, 0.f, 0.f, 0.f};
        #pragma unroll
        for (int k = 0; k < 32; ++k) {
            float gs = gl[ln + k * 64];     // 2-way bank alias: free
            acc.x = fmaf(wrow[k].x, gs, acc.x);
            acc.y = fmaf(wrow[k].y, gs, acc.y);
            acc.z = fmaf(wrow[k].z, gs, acc.z);
            acc.w = fmaf(wrow[k].w, gs, acc.w);
        }
        // plain 64-lane butterfly per component (proven idiom)
        #pragma unroll
        for (int m = 1; m <= 32; m <<= 1) {
            acc.x += __shfl_xor(acc.x, m, 64);
            acc.y += __shfl_xor(acc.y, m, 64);
            acc.z += __shfl_xor(acc.z, m, 64);
            acc.w += __shfl_xor(acc.w, m, 64);
        }

        // ---- neuron updates + publish (owner lane; publish FIRST) ----
        if (own) {
            float sums[4] = {acc.x, acc.y, acc.z, acc.w};
            #pragma unroll
            for (int c = 0; c < 4; ++c) {
                int j = jc0 + c;
                float I      = fmaf(0.9f, xv[c], sums[c]);
                float v_next = v_st[c] + (eL[c] - v_st[c] + I * ri[c]) / tm[c];
                float soft   = 1.0f / (1.0f + expf(30.0f - v_next)); // sigmoid
                bool  spiked = v_next >= 30.0f;
                v_st[c] = spiked ? eL[c] : v_next;
                g_st[c] = spiked ? 1.0f : (g_st[c] - g_st[c] / tg[c]);
                __hip_atomic_store(&slots[(size_t)((t + 1) & 3) * N + j],
                    ((u64)(unsigned)(t + 2) << 32) | (u64)__float_as_uint(g_st[c]),
                    __ATOMIC_RELAXED, __HIP_MEMORY_SCOPE_AGENT);
                out[(size_t)t * N + j] = soft;          // off critical path
                if (t + 1 < T_STEPS) xv[c] = x_in[(size_t)(t + 1) * N + j];
            }
        }
        // no trailing barrier: step t+1 writes the other g_lds buffer, and a
        // wave re-enters this buffer only after the t+1 barrier, which it can
        // reach only after every wave published t+1 (i.e. finished step t).
    }
}

extern "C" void kernel_launch(void* const* d_in, const int* in_sizes, int n_in,
                              void* d_out, int out_size, void* d_ws, size_t ws_size,
                              hipStream_t stream) {
    const float* x_in  = (const float*)d_in[0];
    const float* w     = (const float*)d_in[1];
    const float* E_L   = (const float*)d_in[2];
    const float* tau_m = (const float*)d_in[3];
    const float* R_I   = (const float*)d_in[4];
    const float* tau_g = (const float*)d_in[5];
    const float* v0    = (const float*)d_in[6];
    const float* g0    = (const float*)d_in[7];
    float* out = (float*)d_out;

    u64* slots = (u64*)d_ws;   // 4 slots x 2048 pairs x 8B = 64 KB

    // d_ws re-poisoned to 0xAA each call; tag 0 matches nothing -> zero slots.
    hipMemsetAsync(d_ws, 0, NSLOT * N * sizeof(u64), stream);

    void* args[] = {(void*)&x_in, (void*)&w, (void*)&E_L, (void*)&tau_m,
                    (void*)&R_I, (void*)&tau_g, (void*)&v0, (void*)&g0,
                    (void*)&out, (void*)&slots};
    hipLaunchCooperativeKernel((const void*)lif_kernel, dim3(NBLK), dim3(THREADS),
                               args, 0, stream);
}